// Round 2
// baseline (1110.160 us; speedup 1.0000x reference)
//
#include <hip/hip_runtime.h>

constexpr int B = 32, C = 64, N = 8192, R = 32, R3 = R * R * R;

// ---------------------------------------------------------------------------
// Kernel 1: per-batch stats. One block per batch.
// Mean accumulated in f64 (then cast f32; ~2ulp from numpy's f32 pairwise
// mean -> negligible flip risk). Everything downstream replicates numpy f32
// bit-for-bit: __f*_rn intrinsics forbid FMA contraction, sum order
// ((x*x+y*y)+z*z) matches np.linalg.norm's axis-1 reduce.
// ---------------------------------------------------------------------------
__global__ __launch_bounds__(1024) void stats_kernel(
    const float* __restrict__ coords, float* __restrict__ params) {
  const int b = blockIdx.x;
  const int t = threadIdx.x;
  const float* cb = coords + (size_t)b * 3 * N;
  __shared__ double sm[1024];
  __shared__ float smf[1024];

  double sx = 0.0, sy = 0.0, sz = 0.0;
  for (int n = t; n < N; n += 1024) {
    sx += (double)cb[n];
    sy += (double)cb[N + n];
    sz += (double)cb[2 * N + n];
  }
  float mean[3];
  double vals[3] = {sx, sy, sz};
  for (int d = 0; d < 3; ++d) {
    sm[t] = vals[d];
    __syncthreads();
    for (int s = 512; s > 0; s >>= 1) {
      if (t < s) sm[t] += sm[t + s];
      __syncthreads();
    }
    mean[d] = (float)(sm[0] / (double)N);
    __syncthreads();
  }

  // max of ||c - mean||^2 in exact numpy f32 arithmetic (sqrt is monotone,
  // so reduce on norm^2 and sqrt once at the end).
  float mx = 0.0f;
  for (int n = t; n < N; n += 1024) {
    float dx = __fsub_rn(cb[n], mean[0]);
    float dy = __fsub_rn(cb[N + n], mean[1]);
    float dz = __fsub_rn(cb[2 * N + n], mean[2]);
    float n2 = __fadd_rn(__fadd_rn(__fmul_rn(dx, dx), __fmul_rn(dy, dy)),
                         __fmul_rn(dz, dz));
    mx = fmaxf(mx, n2);
  }
  smf[t] = mx;
  __syncthreads();
  for (int s = 512; s > 0; s >>= 1) {
    if (t < s) smf[t] = fmaxf(smf[t], smf[t + s]);
    __syncthreads();
  }
  if (t == 0) {
    float maxn = __fsqrt_rn(smf[0]);
    params[b * 4 + 0] = mean[0];
    params[b * 4 + 1] = mean[1];
    params[b * 4 + 2] = mean[2];
    params[b * 4 + 3] = __fmul_rn(maxn, 2.0f);  // denominator (EPS == 0)
  }
}

// ---------------------------------------------------------------------------
// Kernel 2: per-point scatter. Thread per (b, n). Exact numpy f32 ops:
// t = ((c - m) / denom + 0.5) * 32, clip [0,31], rintf (half-to-even).
// ---------------------------------------------------------------------------
__global__ __launch_bounds__(256) void scatter_kernel(
    const float* __restrict__ coords, const float* __restrict__ feats,
    const float* __restrict__ params, float* __restrict__ voxout,
    float* __restrict__ ncout, float* __restrict__ cnt) {
  const int i = blockIdx.x * 256 + threadIdx.x;  // [0, B*N)
  const int b = i >> 13;                         // N = 8192
  const int n = i & (N - 1);
  const float* cb = coords + (size_t)b * 3 * N;

  const float m0 = params[b * 4 + 0];
  const float m1 = params[b * 4 + 1];
  const float m2 = params[b * 4 + 2];
  const float denom = params[b * 4 + 3];

  float t0 = __fmul_rn(
      __fadd_rn(__fdiv_rn(__fsub_rn(cb[n], m0), denom), 0.5f), 32.0f);
  float t1 = __fmul_rn(
      __fadd_rn(__fdiv_rn(__fsub_rn(cb[N + n], m1), denom), 0.5f), 32.0f);
  float t2 = __fmul_rn(
      __fadd_rn(__fdiv_rn(__fsub_rn(cb[2 * N + n], m2), denom), 0.5f), 32.0f);
  t0 = fminf(fmaxf(t0, 0.0f), 31.0f);
  t1 = fminf(fmaxf(t1, 0.0f), 31.0f);
  t2 = fminf(fmaxf(t2, 0.0f), 31.0f);

  ncout[(size_t)b * 3 * N + n]         = t0;
  ncout[(size_t)b * 3 * N + N + n]     = t1;
  ncout[(size_t)b * 3 * N + 2 * N + n] = t2;

  const int vx = (int)rintf(t0);  // round-half-to-even == np.round
  const int vy = (int)rintf(t1);
  const int vz = (int)rintf(t2);
  const int flat = (vx * R + vy) * R + vz;

  atomicAdd(&cnt[b * R3 + flat], 1.0f);

  const float* fb = feats + (size_t)b * C * N + n;
  float* ob = voxout + (size_t)b * C * R3 + flat;
#pragma unroll
  for (int c = 0; c < C; ++c) {
    atomicAdd(ob + (size_t)c * R3, fb[(size_t)c * N]);
  }
}

// ---------------------------------------------------------------------------
// Kernel 3: divide sums by counts. Thread per (b, voxel). cnt==0 -> stays 0;
// cnt==1 -> /1 no-op; only cnt>=2 voxels (few %) touch their 64 channels.
// ---------------------------------------------------------------------------
__global__ __launch_bounds__(256) void finalize_kernel(
    float* __restrict__ voxout, const float* __restrict__ cnt) {
  const int i = blockIdx.x * 256 + threadIdx.x;  // [0, B*R3)
  const float c = cnt[i];
  if (c > 1.0f) {
    const int b = i >> 15;  // R3 = 32768
    const int v = i & (R3 - 1);
    float* ob = voxout + (size_t)b * C * R3 + v;
#pragma unroll 4
    for (int ch = 0; ch < C; ++ch) {
      ob[(size_t)ch * R3] = __fdiv_rn(ob[(size_t)ch * R3], c);
    }
  }
}

extern "C" void kernel_launch(void* const* d_in, const int* in_sizes, int n_in,
                              void* d_out, int out_size, void* d_ws,
                              size_t ws_size, hipStream_t stream) {
  const float* feats  = (const float*)d_in[0];  // [B, C, N]
  const float* coords = (const float*)d_in[1];  // [B, 3, N]

  float* voxout = (float*)d_out;                // [B, C, R,R,R]
  float* ncout  = voxout + (size_t)B * C * R3;  // [B, 3, N]

  float* cnt    = (float*)d_ws;                              // B*R3 floats
  float* params = (float*)((char*)d_ws + (size_t)B * R3 * 4);  // B*4 floats

  hipMemsetAsync(voxout, 0, (size_t)B * C * R3 * sizeof(float), stream);
  hipMemsetAsync(cnt, 0, (size_t)B * R3 * sizeof(float), stream);

  stats_kernel<<<B, 1024, 0, stream>>>(coords, params);
  scatter_kernel<<<(B * N) / 256, 256, 0, stream>>>(coords, feats, params,
                                                    voxout, ncout, cnt);
  finalize_kernel<<<(B * R3) / 256, 256, 0, stream>>>(voxout, cnt);
}